// Round 9
// baseline (414.699 us; speedup 1.0000x reference)
//
#include <hip/hip_runtime.h>
#include <hip/hip_bf16.h>

#define CLS 225      // number of classes
#define OPC 224      // outputs per class
#define DIM 1024     // input dim
#define NTOK 1024    // tokens = 8*128
#define VOCAB 50257

#define BM 128       // rows per block (main kernel)
#define BK 32        // K-step
#define NT 14        // 224/16 N-tiles (fallback)

typedef __attribute__((ext_vector_type(8))) short bf16x8;
typedef __attribute__((ext_vector_type(4))) float f32x4;

__device__ __forceinline__ unsigned short f2bf(float f) {
  unsigned u = __float_as_uint(f);
  u += 0x7FFFu + ((u >> 16) & 1u);
  return (unsigned short)(u >> 16);
}

// async global->LDS, 16B per lane. LDS dest = wave-uniform base + lane*16;
// global src is per-lane.
__device__ __forceinline__ void gll16(const void* gsrc, void* ldst) {
  __builtin_amdgcn_global_load_lds(
      (const __attribute__((address_space(1))) void*)gsrc,
      (__attribute__((address_space(3))) void*)ldst, 16, 0, 0);
}

// ---------------- merged prep: W2 convert (blocks 0..7199) + cls softmax
// + X->bf16 swizzled (blocks 7200..7455). One launch, cls overlaps w2 tail.
__global__ __launch_bounds__(256) void hs_prep(
    const float* __restrict__ X, const float* __restrict__ W1,
    const float* __restrict__ b1, float* __restrict__ cls,
    unsigned short* __restrict__ Xws,
    const float* __restrict__ W2, unsigned short* __restrict__ W2ws)
{
  const int bid = blockIdx.x;
  const int tid = threadIdx.x;

  if (bid < CLS * 32) {
    // ---- W2 f32 -> bf16, per-(class,k-tile) swizzled blocks ----
    // Block ct holds W2[c][t*32..t*32+31][0..223] as 224 rows x 64B,
    // byte (o*64 + slot*16) ^ ((o&7)<<4), elems k = t*32 + slot*8 + j.
    const int ct = bid;
    const int c = ct >> 5, t = ct & 31;
    const float* src = W2 + ((size_t)c * DIM + (size_t)t * 32) * OPC;
    char* dst = (char*)(W2ws + (size_t)ct * (OPC * 32));
    for (int i = tid; i < 896; i += 256) {
      const int o = i % OPC, slot = i / OPC;
      const float* p = src + (size_t)(slot * 8) * OPC + o;
      bf16x8 pk;
#pragma unroll
      for (int j = 0; j < 8; ++j) pk[j] = (short)f2bf(p[(size_t)j * OPC]);
      const int wb = (o * 64 + slot * 16) ^ ((o & 7) << 4);
      *(bf16x8*)(dst + wb) = pk;
    }
    return;
  }

  // ---- class softmax (f32, exact) + Xws emit ----
  const int r0 = (bid - CLS * 32) * 4;

  __shared__ float xs[4][DIM];   // 16 KB
  __shared__ float lg[4][CLS];

  {
    const float4* src = (const float4*)(X + (size_t)r0 * DIM);
    float4* dst = (float4*)xs;
    for (int i = tid; i < 4 * DIM / 4; i += 256) dst[i] = src[i];
  }
  __syncthreads();

  // Xws tile t (64KB): byte (n*64 + slot*16) ^ ((n&7)<<4) = X[n][t*32+slot*8+j]
  for (int i = tid; i < 512; i += 256) {
    const int r = i >> 7, grp = i & 127;
    const int t = grp >> 2, slot = grp & 3;
    const int n = r0 + r;
    const float* p = &xs[r][t * 32 + slot * 8];
    bf16x8 pk;
#pragma unroll
    for (int j = 0; j < 8; ++j) pk[j] = (short)f2bf(p[j]);
    const int wb = (n * 64 + slot * 16) ^ ((n & 7) << 4);
    *(bf16x8*)((char*)Xws + (size_t)t * 65536 + wb) = pk;
  }

  if (tid < CLS) {
    float acc0 = 0.f, acc1 = 0.f, acc2 = 0.f, acc3 = 0.f;
    const float* w1p = W1 + tid;
    for (int d = 0; d < DIM; d += 8) {
      float w[8];
#pragma unroll
      for (int u = 0; u < 8; ++u) w[u] = w1p[(size_t)(d + u) * CLS];
#pragma unroll
      for (int u = 0; u < 8; ++u) {
        acc0 += xs[0][d + u] * w[u];
        acc1 += xs[1][d + u] * w[u];
        acc2 += xs[2][d + u] * w[u];
        acc3 += xs[3][d + u] * w[u];
      }
    }
    const float bb = b1[tid];
    lg[0][tid] = acc0 + bb;
    lg[1][tid] = acc1 + bb;
    lg[2][tid] = acc2 + bb;
    lg[3][tid] = acc3 + bb;
  }
  __syncthreads();

  const int wave = tid >> 6, lane = tid & 63;
  {
    const int r = wave;
    float v[4];
    float m = -1e30f;
#pragma unroll
    for (int i = 0; i < 4; ++i) {
      const int c2 = lane + i * 64;
      v[i] = (c2 < CLS) ? lg[r][c2] : -1e30f;
      m = fmaxf(m, v[i]);
    }
#pragma unroll
    for (int mask = 32; mask >= 1; mask >>= 1) m = fmaxf(m, __shfl_xor(m, mask));
    float e[4];
    float s = 0.f;
#pragma unroll
    for (int i = 0; i < 4; ++i) {
      const int c2 = lane + i * 64;
      e[i] = (c2 < CLS) ? __expf(v[i] - m) : 0.f;
      s += e[i];
    }
#pragma unroll
    for (int mask = 32; mask >= 1; mask >>= 1) s += __shfl_xor(s, mask);
    const float inv = 1.f / s;
#pragma unroll
    for (int i = 0; i < 4; ++i) {
      const int c2 = lane + i * 64;
      if (c2 < CLS) cls[(size_t)(r0 + r) * CLS + c2] = e[i] * inv;
    }
  }
}

// standalone cls kernel (fallback path)
__global__ __launch_bounds__(256) void hs_cls_kernel(
    const float* __restrict__ X, const float* __restrict__ W1,
    const float* __restrict__ b1, float* __restrict__ cls)
{
  const int r0 = blockIdx.x * 4;
  const int tid = threadIdx.x;

  __shared__ float xs[4][DIM];
  __shared__ float lg[4][CLS];

  {
    const float4* src = (const float4*)(X + (size_t)r0 * DIM);
    float4* dst = (float4*)xs;
    for (int i = tid; i < 4 * DIM / 4; i += 256) dst[i] = src[i];
  }
  __syncthreads();

  if (tid < CLS) {
    float acc0 = 0.f, acc1 = 0.f, acc2 = 0.f, acc3 = 0.f;
    const float* w1p = W1 + tid;
    for (int d = 0; d < DIM; d += 8) {
      float w[8];
#pragma unroll
      for (int u = 0; u < 8; ++u) w[u] = w1p[(size_t)(d + u) * CLS];
#pragma unroll
      for (int u = 0; u < 8; ++u) {
        acc0 += xs[0][d + u] * w[u];
        acc1 += xs[1][d + u] * w[u];
        acc2 += xs[2][d + u] * w[u];
        acc3 += xs[3][d + u] * w[u];
      }
    }
    const float bb = b1[tid];
    lg[0][tid] = acc0 + bb;
    lg[1][tid] = acc1 + bb;
    lg[2][tid] = acc2 + bb;
    lg[3][tid] = acc3 + bb;
  }
  __syncthreads();

  const int wave = tid >> 6, lane = tid & 63;
  {
    const int r = wave;
    float v[4];
    float m = -1e30f;
#pragma unroll
    for (int i = 0; i < 4; ++i) {
      const int c2 = lane + i * 64;
      v[i] = (c2 < CLS) ? lg[r][c2] : -1e30f;
      m = fmaxf(m, v[i]);
    }
#pragma unroll
    for (int mask = 32; mask >= 1; mask >>= 1) m = fmaxf(m, __shfl_xor(m, mask));
    float e[4];
    float s = 0.f;
#pragma unroll
    for (int i = 0; i < 4; ++i) {
      const int c2 = lane + i * 64;
      e[i] = (c2 < CLS) ? __expf(v[i] - m) : 0.f;
      s += e[i];
    }
#pragma unroll
    for (int mask = 32; mask >= 1; mask >>= 1) s += __shfl_xor(s, mask);
    const float inv = 1.f / s;
#pragma unroll
    for (int i = 0; i < 4; ++i) {
      const int c2 = lane + i * 64;
      if (c2 < CLS) cls[(size_t)(r0 + r) * CLS + c2] = e[i] * inv;
    }
  }
}

// linear Xbf for the fallback path
__global__ __launch_bounds__(256) void x_convert_linear(
    const float* __restrict__ X, unsigned short* __restrict__ Xbf)
{
  const int r0 = blockIdx.x * 16;
  for (int i = threadIdx.x; i < 16 * 128; i += 256) {
    const int r = i >> 7, grp = i & 127;
    const int n = r0 + r;
    const float* p = X + (size_t)n * DIM + grp * 8;
    bf16x8 pk;
#pragma unroll
    for (int j = 0; j < 8; ++j) pk[j] = (short)f2bf(p[j]);
    *(bf16x8*)(Xbf + (size_t)n * DIM + grp * 8) = pk;
  }
}

// ---------------- main: counted-vmcnt dbuf GEMM, 2x2 wave partition ----------------
// grid 29*64: bid -> (g=bid>>6, rt=(bid>>3)&7, xcd=bid&7), c=g*8+xcd.
// Wave (wr,wc) owns 64 rows x 112 cols -> 11 LDS frag reads/wave/K-step.
// Register budget (unified file): acc = 112 AGPR; 2 waves/SIMD requires arch
// VGPR <= ~140 (r5/r7/r8 calibration). Diet: b2 folded into acc INIT (no b2v
// array, no epilogue adds); staging uses running pointers (no per-tile mads).
__global__ __launch_bounds__(256, 1) void hs_main2(
    const unsigned short* __restrict__ W2ws, const float* __restrict__ b2,
    const unsigned short* __restrict__ Xws, const float* __restrict__ cls,
    float* __restrict__ out)
{
  const int bid = blockIdx.x;
  const int g = bid >> 6;
  const int xcd = bid & 7;
  const int rt = (bid >> 3) & 7;
  const int c = g * 8 + xcd;
  if (c >= CLS) return;
  const int n0 = rt * BM;

  // Bs padded to 16 segments (rows 224..255 garbage, never read); source
  // overrun (<=2KB) of the last tile lands in Xws (follows W2ws in ws).
  __shared__ __align__(16) char As[2][8192];
  __shared__ __align__(16) char Bs[2][16384];
  __shared__ float2 red[4][64];   // per-wave partial (max,sum) per row

  const int tid = threadIdx.x;
  const int wv = tid >> 6, lane = tid & 63;
  const int lo16 = lane & 15, hi4 = lane >> 4;
  const int wr = wv >> 1, wc = wv & 1;
  const int loff = lane * 16;

  // acc init = b2 broadcast (b2 added exactly once; epilogue has no adds)
  f32x4 acc[4][7];
#pragma unroll
  for (int nt = 0; nt < 7; ++nt) {
    const float bb = b2[c * OPC + wc * 112 + nt * 16 + lo16];
#pragma unroll
    for (int m = 0; m < 4; ++m) acc[m][nt] = (f32x4){bb, bb, bb, bb};
  }
  // drain the b2 loads so the counted-vmcnt protocol below starts clean
  asm volatile("s_waitcnt vmcnt(0)" ::: "memory");
  __builtin_amdgcn_sched_barrier(0);

  // per-wave staging segments: s = wv*6+i; s<8 -> A seg s, else B seg s-8.
  // Running pointers advance by one tile's stride per STAGE (no index math).
  const char* xb  = (const char*)Xws + (size_t)n0 * 64 + loff;
  const char* wb2 = (const char*)W2ws + (size_t)c * 32 * 14336 + loff;
#define SEGDEF(i)                                                              \
  const int s_##i = wv * 6 + i;                                                \
  const bool isA_##i = (s_##i < 8);                                            \
  const char* p_##i = isA_##i ? (xb + s_##i * 1024) : (wb2 + (s_##i - 8) * 1024); \
  const int st_##i = isA_##i ? 65536 : 14336;                                  \
  const int ldo_##i = isA_##i ? s_##i * 1024 : (s_##i - 8) * 1024;
  SEGDEF(0) SEGDEF(1) SEGDEF(2) SEGDEF(3) SEGDEF(4) SEGDEF(5)

#define STG(i, buf)                                                            \
  do {                                                                         \
    gll16(p_##i, (isA_##i ? As[buf] : Bs[buf]) + ldo_##i);                     \
    p_##i += st_##i;                                                           \
  } while (0)
#define STAGE(buf)                                                             \
  { STG(0, buf); STG(1, buf); STG(2, buf); STG(3, buf); STG(4, buf); STG(5, buf); }

#define COMPUTE(buf)                                                           \
  {                                                                            \
    const char* Ac = As[buf];                                                  \
    const char* Bc = Bs[buf];                                                  \
    const int axor = (lo16 & 7) << 4;                                          \
    bf16x8 Af[4];                                                              \
    _Pragma("unroll")                                                          \
    for (int m = 0; m < 4; ++m) {                                              \
      const int ra = wr * 64 + m * 16 + lo16;                                  \
      Af[m] = *(const bf16x8*)(Ac + ((ra * 64 + hi4 * 16) ^ axor));            \
    }                                                                          \
    _Pragma("unroll")                                                          \
    for (int nt = 0; nt < 7; ++nt) {                                           \
      const int o = wc * 112 + nt * 16 + lo16;                                 \
      const bf16x8 vb = *(const bf16x8*)(Bc + ((o * 64 + hi4 * 16) ^ axor));   \
      _Pragma("unroll")                                                        \
      for (int m = 0; m < 4; ++m)                                              \
        acc[m][nt] = __builtin_amdgcn_mfma_f32_16x16x32_bf16(Af[m], vb,        \
                                                             acc[m][nt], 0, 0, 0); \
    }                                                                          \
  }

  STAGE(0);                          // tile 0 -> buf0 (6 loads/wave)
  STAGE(1);                          // tile 1 -> buf1 (12 outstanding)

  for (int t = 0; t < 31; ++t) {
    // own tile-t loads done; tile-(t+1)'s 6 stay in flight (never drain to 0)
    asm volatile("s_waitcnt vmcnt(6)" ::: "memory");
    __builtin_amdgcn_s_barrier();
    __builtin_amdgcn_sched_barrier(0);   // pin ds_reads after the barrier

    COMPUTE(t & 1);

    __builtin_amdgcn_sched_barrier(0);   // pin compute before the barrier
    __builtin_amdgcn_s_barrier();        // all waves done reading buf[t&1]
    if (t < 30) STAGE(t & 1);            // overwrite it with tile t+2
  }
  // tail: tile 31 (in buf1), 6 loads outstanding
  asm volatile("s_waitcnt vmcnt(0)" ::: "memory");
  __builtin_amdgcn_s_barrier();
  __builtin_amdgcn_sched_barrier(0);
  COMPUTE(1);

#undef STAGE
#undef STG
#undef SEGDEF
#undef COMPUTE

  // ---- epilogue: partial softmax (exp in place), LDS merge, scale, store ----
  // loop A: per row partial max & sum; exponentiate acc in place; partials
  // to red[] (no per-row registers survive).
#pragma unroll
  for (int m = 0; m < 4; ++m) {
#pragma unroll
    for (int j = 0; j < 4; ++j) {
      float mx = -1e30f;
#pragma unroll
      for (int nt = 0; nt < 7; ++nt) mx = fmaxf(mx, acc[m][nt][j]);
#pragma unroll
      for (int mask = 8; mask >= 1; mask >>= 1) mx = fmaxf(mx, __shfl_xor(mx, mask));
      float s = 0.f;
#pragma unroll
      for (int nt = 0; nt < 7; ++nt) {
        const float v = __expf(acc[m][nt][j] - mx);
        acc[m][nt][j] = v;
        s += v;
      }
#pragma unroll
      for (int mask = 8; mask >= 1; mask >>= 1) s += __shfl_xor(s, mask);
      if (lo16 == 0) red[wv][m * 16 + hi4 * 4 + j] = make_float2(mx, s);
    }
  }
  __syncthreads();

  // loop B: re-read own partial (broadcast), merge with sibling wave, store.
#pragma unroll
  for (int m = 0; m < 4; ++m) {
#pragma unroll
    for (int j = 0; j < 4; ++j) {
      const int rloc = m * 16 + hi4 * 4 + j;
      const float2 own = red[wv][rloc];
      const float2 ot = red[wv ^ 1][rloc];
      const float gm = fmaxf(own.x, ot.x);
      const float stot = own.y * __expf(own.x - gm) + ot.y * __expf(ot.x - gm);
      const int n = n0 + wr * 64 + rloc;
      const float scale = cls[(size_t)n * CLS + c] * __expf(own.x - gm) / stot;
      const size_t rowbase = (size_t)n * VOCAB;
      const int colbase = c * OPC + wc * 112 + lo16;
#pragma unroll
      for (int nt = 0; nt < 7; ++nt) {
        const int col = colbase + nt * 16;
        if (col < VOCAB)
          __builtin_nontemporal_store(acc[m][nt][j] * scale, out + rowbase + col);
      }
    }
  }
}

// ---------------- fallback main (round-1, known-passing): inline convert ----------------
__global__ __launch_bounds__(256, 1) void hs_main_fallback(
    const float* __restrict__ W2, const float* __restrict__ b2,
    const unsigned short* __restrict__ Xbf, const float* __restrict__ cls,
    float* __restrict__ out)
{
  const int bid = blockIdx.x;
  const int g = bid >> 6;
  const int xcd = bid & 7;
  const int rt = (bid >> 3) & 7;
  const int c = g * 8 + xcd;
  if (c >= CLS) return;
  const int n0 = rt * BM;
  const float* __restrict__ W2c = W2 + (size_t)c * DIM * OPC;

  __shared__ __align__(16) char As[BM * BK * 2];
  __shared__ __align__(16) char Bs[OPC * BK * 2];

  const int tid = threadIdx.x;
  const int wv = tid >> 6, lane = tid & 63;
  const int lo16 = lane & 15, hi4 = lane >> 4;

  f32x4 acc[2][NT];
#pragma unroll
  for (int mt = 0; mt < 2; ++mt)
#pragma unroll
    for (int nt = 0; nt < NT; ++nt) acc[mt][nt] = (f32x4){0.f, 0.f, 0.f, 0.f};

  const int an0 = tid >> 2;
  const int akp = tid & 3;

  for (int k0 = 0; k0 < DIM; k0 += BK) {
    __syncthreads();
#pragma unroll
    for (int r = 0; r < 2; ++r) {
      const int n = an0 + r * 64;
      const uint4 raw = *(const uint4*)(Xbf + (size_t)(n0 + n) * DIM + k0 + akp * 8);
      const int wb = (n * 64 + akp * 16) ^ ((n & 7) << 4);
      *(uint4*)(As + wb) = raw;
    }
#pragma unroll
    for (int r = 0; r < 4; ++r) {
      const int t = tid + r * 256;
      if (t < 896) {
        const int o = t % OPC;
        const int kg = t / OPC;
        const float* p = W2c + (size_t)(k0 + kg * 8) * OPC + o;
        bf16x8 pk;
#pragma unroll
        for (int j = 0; j < 8; ++j) pk[j] = (short)f2bf(p[(size_t)j * OPC]);
        const int wb = (o * 64 + kg * 16) ^ ((o & 7) << 4);
        *(bf16x8*)(Bs + wb) = pk;
      }
    }
    __syncthreads();

    const int ra = wv * 32 + lo16;
    const int axor = (lo16 & 7) << 4;
    const bf16x8 a0 = *(const bf16x8*)(As + ((ra * 64 + hi4 * 16) ^ axor));
    const bf16x8 a1 = *(const bf16x8*)(As + (((ra + 16) * 64 + hi4 * 16) ^ axor));
#pragma unroll
    for (int nt = 0; nt < NT; ++nt) {
      const int o = nt * 16 + lo16;
      const bf16x8 b = *(const bf16x8*)(Bs + ((o * 64 + hi4 * 16) ^ ((o & 7) << 4)));
      acc[0][nt] = __builtin_amdgcn_mfma_f32_16x16x32_bf16(a0, b, acc[0][nt], 0, 0, 0);
      acc[1][nt] = __builtin_amdgcn_mfma_f32_16x16x32_bf16(a1, b, acc[1][nt], 0, 0, 0);
    }
  }

  float b2v[NT];
#pragma unroll
  for (int nt = 0; nt < NT; ++nt) b2v[nt] = b2[c * OPC + nt * 16 + lo16];

#pragma unroll
  for (int mt = 0; mt < 2; ++mt) {
#pragma unroll
    for (int j = 0; j < 4; ++j) {
      const int n = n0 + wv * 32 + mt * 16 + hi4 * 4 + j;
      float vv[NT];
      float m = -1e30f;
#pragma unroll
      for (int nt = 0; nt < NT; ++nt) {
        vv[nt] = acc[mt][nt][j] + b2v[nt];
        m = fmaxf(m, vv[nt]);
      }
#pragma unroll
      for (int mask = 8; mask >= 1; mask >>= 1) m = fmaxf(m, __shfl_xor(m, mask));
      float s = 0.f;
#pragma unroll
      for (int nt = 0; nt < NT; ++nt) {
        vv[nt] = __expf(vv[nt] - m);
        s += vv[nt];
      }
#pragma unroll
      for (int mask = 8; mask >= 1; mask >>= 1) s += __shfl_xor(s, mask);
      const float scale = cls[(size_t)n * CLS + c] / s;
      const size_t rowbase = (size_t)n * VOCAB;
      const int colbase = c * OPC + lo16;
#pragma unroll
      for (int nt = 0; nt < NT; ++nt) {
        const int col = colbase + nt * 16;
        if (col < VOCAB)
          __builtin_nontemporal_store(vv[nt] * scale, out + rowbase + col);
      }
    }
  }
}

extern "C" void kernel_launch(void* const* d_in, const int* in_sizes, int n_in,
                              void* d_out, int out_size, void* d_ws, size_t ws_size,
                              hipStream_t stream) {
  const float* X  = (const float*)d_in[0];
  const float* W1 = (const float*)d_in[1];
  const float* b1 = (const float*)d_in[2];
  const float* W2 = (const float*)d_in[3];
  const float* b2 = (const float*)d_in[4];
  float* out = (float*)d_out;

  const size_t W2WS = (size_t)CLS * DIM * OPC * 2;   // 103,219,200 B
  const size_t XWS  = (size_t)NTOK * DIM * 2;        //   2,097,152 B (also absorbs B-stage overrun)
  const size_t CLSZ = (size_t)NTOK * CLS * 4;        //     921,600 B

  if (ws_size >= W2WS + XWS + CLSZ) {
    unsigned short* W2ws = (unsigned short*)d_ws;
    unsigned short* Xws  = (unsigned short*)((char*)d_ws + W2WS);
    float* cls = (float*)((char*)d_ws + W2WS + XWS);

    hs_prep<<<CLS * 32 + NTOK / 4, 256, 0, stream>>>(X, W1, b1, cls, Xws, W2, W2ws);
    hs_main2<<<29 * 64, 256, 0, stream>>>(W2ws, b2, Xws, cls, out);
  } else {
    unsigned short* Xbf = (unsigned short*)d_ws;
    float* cls = (float*)((char*)d_ws + (size_t)NTOK * DIM * 2);

    x_convert_linear<<<NTOK / 16, 256, 0, stream>>>(X, Xbf);
    hs_cls_kernel<<<NTOK / 4, 256, 0, stream>>>(X, W1, b1, cls);
    hs_main_fallback<<<29 * 64, 256, 0, stream>>>(W2, b2, Xbf, cls, out);
  }
}

// Round 10
// 293.746 us; speedup vs baseline: 1.4118x; 1.4118x over previous
//
#include <hip/hip_runtime.h>
#include <hip/hip_bf16.h>

#define CLS 225      // number of classes
#define OPC 224      // outputs per class
#define DIM 1024     // input dim
#define NTOK 1024    // tokens = 8*128
#define VOCAB 50257

#define BM 128       // rows per block (main kernel)
#define BK 32        // K-step
#define NT 14        // 224/16 N-tiles

typedef __attribute__((ext_vector_type(8))) short bf16x8;
typedef __attribute__((ext_vector_type(4))) float f32x4;

__device__ __forceinline__ unsigned short f2bf(float f) {
  unsigned u = __float_as_uint(f);
  u += 0x7FFFu + ((u >> 16) & 1u);
  return (unsigned short)(u >> 16);
}

// async global->LDS, 16B per lane. LDS dest = wave-uniform base + lane*16;
// global src is per-lane.
__device__ __forceinline__ void gll16(const void* gsrc, void* ldst) {
  __builtin_amdgcn_global_load_lds(
      (const __attribute__((address_space(1))) void*)gsrc,
      (__attribute__((address_space(3))) void*)ldst, 16, 0, 0);
}

// ---------------- merged prep: W2 convert (blocks 0..3599, 2 k-tiles each)
// + cls softmax + X->bf16 swizzled (blocks 3600..3855). One launch.
__global__ __launch_bounds__(256) void hs_prep(
    const float* __restrict__ X, const float* __restrict__ W1,
    const float* __restrict__ b1, float* __restrict__ cls,
    unsigned short* __restrict__ Xws,
    const float* __restrict__ W2, unsigned short* __restrict__ W2ws)
{
  const int bid = blockIdx.x;
  const int tid = threadIdx.x;

  if (bid < CLS * 16) {
    // ---- W2 f32 -> bf16, per-(class,k-tile) swizzled blocks, 2 tiles/block ----
    // Block ct holds W2[c][t*32..t*32+31][0..223] as 224 rows x 64B,
    // byte (o*64 + slot*16) ^ ((o&7)<<4), elems k = t*32 + slot*8 + j.
    const int ct0 = bid * 2;
    for (int i = tid; i < 1792; i += 256) {     // 7 full iterations, no idle lanes
      const int half = (i >= 896);
      const int e = i - half * 896;
      const int ct = ct0 + half;
      const int c = ct >> 5, t = ct & 31;
      const float* src = W2 + ((size_t)c * DIM + (size_t)t * 32) * OPC;
      char* dst = (char*)(W2ws + (size_t)ct * (OPC * 32));
      const int o = e % OPC, slot = e / OPC;
      const float* p = src + (size_t)(slot * 8) * OPC + o;
      bf16x8 pk;
#pragma unroll
      for (int j = 0; j < 8; ++j) pk[j] = (short)f2bf(p[(size_t)j * OPC]);
      const int wb = (o * 64 + slot * 16) ^ ((o & 7) << 4);
      *(bf16x8*)(dst + wb) = pk;
    }
    return;
  }

  // ---- class softmax (f32, exact) + Xws emit ----
  const int r0 = (bid - CLS * 16) * 4;

  __shared__ float xs[4][DIM];   // 16 KB
  __shared__ float lg[4][CLS];

  {
    const float4* src = (const float4*)(X + (size_t)r0 * DIM);
    float4* dst = (float4*)xs;
    for (int i = tid; i < 4 * DIM / 4; i += 256) dst[i] = src[i];
  }
  __syncthreads();

  // Xws tile t (64KB): byte (n*64 + slot*16) ^ ((n&7)<<4) = X[n][t*32+slot*8+j]
  for (int i = tid; i < 512; i += 256) {
    const int r = i >> 7, grp = i & 127;
    const int t = grp >> 2, slot = grp & 3;
    const int n = r0 + r;
    const float* p = &xs[r][t * 32 + slot * 8];
    bf16x8 pk;
#pragma unroll
    for (int j = 0; j < 8; ++j) pk[j] = (short)f2bf(p[j]);
    const int wb = (n * 64 + slot * 16) ^ ((n & 7) << 4);
    *(bf16x8*)((char*)Xws + (size_t)t * 65536 + wb) = pk;
  }

  if (tid < CLS) {
    float acc0 = 0.f, acc1 = 0.f, acc2 = 0.f, acc3 = 0.f;
    const float* w1p = W1 + tid;
    for (int d = 0; d < DIM; d += 8) {
      float w[8];
#pragma unroll
      for (int u = 0; u < 8; ++u) w[u] = w1p[(size_t)(d + u) * CLS];
#pragma unroll
      for (int u = 0; u < 8; ++u) {
        acc0 += xs[0][d + u] * w[u];
        acc1 += xs[1][d + u] * w[u];
        acc2 += xs[2][d + u] * w[u];
        acc3 += xs[3][d + u] * w[u];
      }
    }
    const float bb = b1[tid];
    lg[0][tid] = acc0 + bb;
    lg[1][tid] = acc1 + bb;
    lg[2][tid] = acc2 + bb;
    lg[3][tid] = acc3 + bb;
  }
  __syncthreads();

  const int wave = tid >> 6, lane = tid & 63;
  {
    const int r = wave;
    float v[4];
    float m = -1e30f;
#pragma unroll
    for (int i = 0; i < 4; ++i) {
      const int c2 = lane + i * 64;
      v[i] = (c2 < CLS) ? lg[r][c2] : -1e30f;
      m = fmaxf(m, v[i]);
    }
#pragma unroll
    for (int mask = 32; mask >= 1; mask >>= 1) m = fmaxf(m, __shfl_xor(m, mask));
    float e[4];
    float s = 0.f;
#pragma unroll
    for (int i = 0; i < 4; ++i) {
      const int c2 = lane + i * 64;
      e[i] = (c2 < CLS) ? __expf(v[i] - m) : 0.f;
      s += e[i];
    }
#pragma unroll
    for (int mask = 32; mask >= 1; mask >>= 1) s += __shfl_xor(s, mask);
    const float inv = 1.f / s;
#pragma unroll
    for (int i = 0; i < 4; ++i) {
      const int c2 = lane + i * 64;
      if (c2 < CLS) cls[(size_t)(r0 + r) * CLS + c2] = e[i] * inv;
    }
  }
}

// standalone cls kernel (fallback path)
__global__ __launch_bounds__(256) void hs_cls_kernel(
    const float* __restrict__ X, const float* __restrict__ W1,
    const float* __restrict__ b1, float* __restrict__ cls)
{
  const int r0 = blockIdx.x * 4;
  const int tid = threadIdx.x;

  __shared__ float xs[4][DIM];
  __shared__ float lg[4][CLS];

  {
    const float4* src = (const float4*)(X + (size_t)r0 * DIM);
    float4* dst = (float4*)xs;
    for (int i = tid; i < 4 * DIM / 4; i += 256) dst[i] = src[i];
  }
  __syncthreads();

  if (tid < CLS) {
    float acc0 = 0.f, acc1 = 0.f, acc2 = 0.f, acc3 = 0.f;
    const float* w1p = W1 + tid;
    for (int d = 0; d < DIM; d += 8) {
      float w[8];
#pragma unroll
      for (int u = 0; u < 8; ++u) w[u] = w1p[(size_t)(d + u) * CLS];
#pragma unroll
      for (int u = 0; u < 8; ++u) {
        acc0 += xs[0][d + u] * w[u];
        acc1 += xs[1][d + u] * w[u];
        acc2 += xs[2][d + u] * w[u];
        acc3 += xs[3][d + u] * w[u];
      }
    }
    const float bb = b1[tid];
    lg[0][tid] = acc0 + bb;
    lg[1][tid] = acc1 + bb;
    lg[2][tid] = acc2 + bb;
    lg[3][tid] = acc3 + bb;
  }
  __syncthreads();

  const int wave = tid >> 6, lane = tid & 63;
  {
    const int r = wave;
    float v[4];
    float m = -1e30f;
#pragma unroll
    for (int i = 0; i < 4; ++i) {
      const int c2 = lane + i * 64;
      v[i] = (c2 < CLS) ? lg[r][c2] : -1e30f;
      m = fmaxf(m, v[i]);
    }
#pragma unroll
    for (int mask = 32; mask >= 1; mask >>= 1) m = fmaxf(m, __shfl_xor(m, mask));
    float e[4];
    float s = 0.f;
#pragma unroll
    for (int i = 0; i < 4; ++i) {
      const int c2 = lane + i * 64;
      e[i] = (c2 < CLS) ? __expf(v[i] - m) : 0.f;
      s += e[i];
    }
#pragma unroll
    for (int mask = 32; mask >= 1; mask >>= 1) s += __shfl_xor(s, mask);
    const float inv = 1.f / s;
#pragma unroll
    for (int i = 0; i < 4; ++i) {
      const int c2 = lane + i * 64;
      if (c2 < CLS) cls[(size_t)(r0 + r) * CLS + c2] = e[i] * inv;
    }
  }
}

// linear Xbf for the fallback path
__global__ __launch_bounds__(256) void x_convert_linear(
    const float* __restrict__ X, unsigned short* __restrict__ Xbf)
{
  const int r0 = blockIdx.x * 16;
  for (int i = threadIdx.x; i < 16 * 128; i += 256) {
    const int r = i >> 7, grp = i & 127;
    const int n = r0 + r;
    const float* p = X + (size_t)n * DIM + grp * 8;
    bf16x8 pk;
#pragma unroll
    for (int j = 0; j < 8; ++j) pk[j] = (short)f2bf(p[j]);
    *(bf16x8*)(Xbf + (size_t)n * DIM + grp * 8) = pk;
  }
}

// ---------------- main: counted-vmcnt double-buffered GEMM + fused softmax ----------------
// EXACT round-5 structure (measured 170 us, VGPR 128, occupancy 19.4%):
// row partition (wave wv owns rows [wv*32, wv*32+32)), 2 A-frags + 14 B-frags,
// T4 counted vmcnt(6), raw barriers, b2v epilogue with 16-lane shfl softmax.
__global__ __launch_bounds__(256, 1) void hs_main2(
    const unsigned short* __restrict__ W2ws, const float* __restrict__ b2,
    const unsigned short* __restrict__ Xws, const float* __restrict__ cls,
    float* __restrict__ out)
{
  const int bid = blockIdx.x;
  const int g = bid >> 6;
  const int xcd = bid & 7;
  const int rt = (bid >> 3) & 7;
  const int c = g * 8 + xcd;
  if (c >= CLS) return;
  const int n0 = rt * BM;

  // Bs padded to 16 segments (rows 224..255 garbage, never read); source
  // overrun (<=2KB) of the last tile lands in Xws (follows W2ws in ws).
  __shared__ __align__(16) char As[2][8192];
  __shared__ __align__(16) char Bs[2][16384];

  const int tid = threadIdx.x;
  const int wv = tid >> 6, lane = tid & 63;
  const int lo16 = lane & 15, hi4 = lane >> 4;
  const int loff = lane * 16;

  f32x4 acc[2][NT];
#pragma unroll
  for (int mt = 0; mt < 2; ++mt)
#pragma unroll
    for (int nt = 0; nt < NT; ++nt) acc[mt][nt] = (f32x4){0.f, 0.f, 0.f, 0.f};

  // per-wave staging segments: s = wv*6+i; s<8 -> A seg s, else B seg s-8.
  const char* xb  = (const char*)Xws + (size_t)n0 * 64 + loff;
  const char* wb2 = (const char*)W2ws + (size_t)c * 32 * 14336 + loff;
#define SEGDEF(i)                                                              \
  const int s_##i = wv * 6 + i;                                                \
  const bool isA_##i = (s_##i < 8);                                            \
  const char* g_##i = isA_##i ? (xb + s_##i * 1024) : (wb2 + (s_##i - 8) * 1024); \
  const size_t gstr_##i = isA_##i ? 65536u : 14336u;                           \
  const int ldo_##i = isA_##i ? s_##i * 1024 : (s_##i - 8) * 1024;
  SEGDEF(0) SEGDEF(1) SEGDEF(2) SEGDEF(3) SEGDEF(4) SEGDEF(5)

#define STG(i, buf, t)                                                         \
  gll16(g_##i + (size_t)(t) * gstr_##i, (isA_##i ? As[buf] : Bs[buf]) + ldo_##i)
#define STAGE(buf, t)                                                          \
  { STG(0, buf, t); STG(1, buf, t); STG(2, buf, t); STG(3, buf, t);            \
    STG(4, buf, t); STG(5, buf, t); }

#define COMPUTE(buf)                                                           \
  {                                                                            \
    const char* Ac = As[buf];                                                  \
    const char* Bc = Bs[buf];                                                  \
    const int ra = wv * 32 + lo16;                                             \
    const int axor = (lo16 & 7) << 4;                                          \
    const bf16x8 va0 = *(const bf16x8*)(Ac + ((ra * 64 + hi4 * 16) ^ axor));   \
    const bf16x8 va1 = *(const bf16x8*)(Ac + (((ra + 16) * 64 + hi4 * 16) ^ axor)); \
    _Pragma("unroll")                                                          \
    for (int nt = 0; nt < NT; ++nt) {                                          \
      const int o = nt * 16 + lo16;                                            \
      const bf16x8 vb = *(const bf16x8*)(Bc + ((o * 64 + hi4 * 16) ^ ((o & 7) << 4))); \
      acc[0][nt] = __builtin_amdgcn_mfma_f32_16x16x32_bf16(va0, vb, acc[0][nt], 0, 0, 0); \
      acc[1][nt] = __builtin_amdgcn_mfma_f32_16x16x32_bf16(va1, vb, acc[1][nt], 0, 0, 0); \
    }                                                                          \
  }

  STAGE(0, 0);                       // tile 0 -> buf0 (6 loads)
  STAGE(1, 1);                       // tile 1 -> buf1 (12 outstanding)

  for (int t = 0; t < 31; ++t) {
    // own tile-t loads done; tile-(t+1)'s 6 stay in flight (never drain to 0)
    asm volatile("s_waitcnt vmcnt(6)" ::: "memory");
    __builtin_amdgcn_s_barrier();
    __builtin_amdgcn_sched_barrier(0);   // pin ds_reads after the barrier

    COMPUTE(t & 1);

    __builtin_amdgcn_sched_barrier(0);   // pin compute before the barrier
    __builtin_amdgcn_s_barrier();        // all waves done reading buf[t&1]
    if (t < 30) STAGE(t & 1, t + 2);     // overwrite it with tile t+2
  }
  // tail: tile 31 (in buf1), 6 loads outstanding
  asm volatile("s_waitcnt vmcnt(0)" ::: "memory");
  __builtin_amdgcn_s_barrier();
  __builtin_amdgcn_sched_barrier(0);
  COMPUTE(1);

#undef STAGE
#undef STG
#undef SEGDEF
#undef COMPUTE

  // ---- epilogue: +b2, row softmax over 224, scale by class prob, store ----
  float b2v[NT];
#pragma unroll
  for (int nt = 0; nt < NT; ++nt) b2v[nt] = b2[c * OPC + nt * 16 + lo16];

#pragma unroll
  for (int mt = 0; mt < 2; ++mt) {
#pragma unroll
    for (int j = 0; j < 4; ++j) {
      const int n = n0 + wv * 32 + mt * 16 + hi4 * 4 + j;
      float vv[NT];
      float m = -1e30f;
#pragma unroll
      for (int nt = 0; nt < NT; ++nt) {
        vv[nt] = acc[mt][nt][j] + b2v[nt];
        m = fmaxf(m, vv[nt]);
      }
#pragma unroll
      for (int mask = 8; mask >= 1; mask >>= 1) m = fmaxf(m, __shfl_xor(m, mask));
      float s = 0.f;
#pragma unroll
      for (int nt = 0; nt < NT; ++nt) {
        vv[nt] = __expf(vv[nt] - m);
        s += vv[nt];
      }
#pragma unroll
      for (int mask = 8; mask >= 1; mask >>= 1) s += __shfl_xor(s, mask);
      const float scale = cls[(size_t)n * CLS + c] / s;
      const size_t rowbase = (size_t)n * VOCAB;
      const int colbase = c * OPC + lo16;
#pragma unroll
      for (int nt = 0; nt < NT; ++nt) {
        const int col = colbase + nt * 16;
        if (col < VOCAB)
          __builtin_nontemporal_store(vv[nt] * scale, out + rowbase + col);
      }
    }
  }
}

// ---------------- fallback main (round-1, known-passing): inline convert ----------------
__global__ __launch_bounds__(256, 1) void hs_main_fallback(
    const float* __restrict__ W2, const float* __restrict__ b2,
    const unsigned short* __restrict__ Xbf, const float* __restrict__ cls,
    float* __restrict__ out)
{
  const int bid = blockIdx.x;
  const int g = bid >> 6;
  const int xcd = bid & 7;
  const int rt = (bid >> 3) & 7;
  const int c = g * 8 + xcd;
  if (c >= CLS) return;
  const int n0 = rt * BM;
  const float* __restrict__ W2c = W2 + (size_t)c * DIM * OPC;

  __shared__ __align__(16) char As[BM * BK * 2];
  __shared__ __align__(16) char Bs[OPC * BK * 2];

  const int tid = threadIdx.x;
  const int wv = tid >> 6, lane = tid & 63;
  const int lo16 = lane & 15, hi4 = lane >> 4;

  f32x4 acc[2][NT];
#pragma unroll
  for (int mt = 0; mt < 2; ++mt)
#pragma unroll
    for (int nt = 0; nt < NT; ++nt) acc[mt][nt] = (f32x4){0.f, 0.f, 0.f, 0.f};

  const int an0 = tid >> 2;
  const int akp = tid & 3;

  for (int k0 = 0; k0 < DIM; k0 += BK) {
    __syncthreads();
#pragma unroll
    for (int r = 0; r < 2; ++r) {
      const int n = an0 + r * 64;
      const uint4 raw = *(const uint4*)(Xbf + (size_t)(n0 + n) * DIM + k0 + akp * 8);
      const int wb = (n * 64 + akp * 16) ^ ((n & 7) << 4);
      *(uint4*)(As + wb) = raw;
    }
#pragma unroll
    for (int r = 0; r < 4; ++r) {
      const int t = tid + r * 256;
      if (t < 896) {
        const int o = t % OPC;
        const int kg = t / OPC;
        const float* p = W2c + (size_t)(k0 + kg * 8) * OPC + o;
        bf16x8 pk;
#pragma unroll
        for (int j = 0; j < 8; ++j) pk[j] = (short)f2bf(p[(size_t)j * OPC]);
        const int wb = (o * 64 + kg * 16) ^ ((o & 7) << 4);
        *(bf16x8*)(Bs + wb) = pk;
      }
    }
    __syncthreads();

    const int ra = wv * 32 + lo16;
    const int axor = (lo16 & 7) << 4;
    const bf16x8 a0 = *(const bf16x8*)(As + ((ra * 64 + hi4 * 16) ^ axor));
    const bf16x8 a1 = *(const bf16x8*)(As + (((ra + 16) * 64 + hi4 * 16) ^ axor));
#pragma unroll
    for (int nt = 0; nt < NT; ++nt) {
      const int o = nt * 16 + lo16;
      const bf16x8 b = *(const bf16x8*)(Bs + ((o * 64 + hi4 * 16) ^ ((o & 7) << 4)));
      acc[0][nt] = __builtin_amdgcn_mfma_f32_16x16x32_bf16(a0, b, acc[0][nt], 0, 0, 0);
      acc[1][nt] = __builtin_amdgcn_mfma_f32_16x16x32_bf16(a1, b, acc[1][nt], 0, 0, 0);
    }
  }

  float b2v[NT];
#pragma unroll
  for (int nt = 0; nt < NT; ++nt) b2v[nt] = b2[c * OPC + nt * 16 + lo16];

#pragma unroll
  for (int mt = 0; mt < 2; ++mt) {
#pragma unroll
    for (int j = 0; j < 4; ++j) {
      const int n = n0 + wv * 32 + mt * 16 + hi4 * 4 + j;
      float vv[NT];
      float m = -1e30f;
#pragma unroll
      for (int nt = 0; nt < NT; ++nt) {
        vv[nt] = acc[mt][nt][j] + b2v[nt];
        m = fmaxf(m, vv[nt]);
      }
#pragma unroll
      for (int mask = 8; mask >= 1; mask >>= 1) m = fmaxf(m, __shfl_xor(m, mask));
      float s = 0.f;
#pragma unroll
      for (int nt = 0; nt < NT; ++nt) {
        vv[nt] = __expf(vv[nt] - m);
        s += vv[nt];
      }
#pragma unroll
      for (int mask = 8; mask >= 1; mask >>= 1) s += __shfl_xor(s, mask);
      const float scale = cls[(size_t)n * CLS + c] / s;
      const size_t rowbase = (size_t)n * VOCAB;
      const int colbase = c * OPC + lo16;
#pragma unroll
      for (int nt = 0; nt < NT; ++nt) {
        const int col = colbase + nt * 16;
        if (col < VOCAB)
          __builtin_nontemporal_store(vv[nt] * scale, out + rowbase + col);
      }
    }
  }
}

extern "C" void kernel_launch(void* const* d_in, const int* in_sizes, int n_in,
                              void* d_out, int out_size, void* d_ws, size_t ws_size,
                              hipStream_t stream) {
  const float* X  = (const float*)d_in[0];
  const float* W1 = (const float*)d_in[1];
  const float* b1 = (const float*)d_in[2];
  const float* W2 = (const float*)d_in[3];
  const float* b2 = (const float*)d_in[4];
  float* out = (float*)d_out;

  const size_t W2WS = (size_t)CLS * DIM * OPC * 2;   // 103,219,200 B
  const size_t XWS  = (size_t)NTOK * DIM * 2;        //   2,097,152 B (also absorbs B-stage overrun)
  const size_t CLSZ = (size_t)NTOK * CLS * 4;        //     921,600 B

  if (ws_size >= W2WS + XWS + CLSZ) {
    unsigned short* W2ws = (unsigned short*)d_ws;
    unsigned short* Xws  = (unsigned short*)((char*)d_ws + W2WS);
    float* cls = (float*)((char*)d_ws + W2WS + XWS);

    hs_prep<<<CLS * 16 + NTOK / 4, 256, 0, stream>>>(X, W1, b1, cls, Xws, W2, W2ws);
    hs_main2<<<29 * 64, 256, 0, stream>>>(W2ws, b2, Xws, cls, out);
  } else {
    unsigned short* Xbf = (unsigned short*)d_ws;
    float* cls = (float*)((char*)d_ws + (size_t)NTOK * DIM * 2);

    x_convert_linear<<<NTOK / 16, 256, 0, stream>>>(X, Xbf);
    hs_cls_kernel<<<NTOK / 4, 256, 0, stream>>>(X, W1, b1, cls);
    hs_main_fallback<<<29 * 64, 256, 0, stream>>>(W2, b2, Xbf, cls, out);
  }
}

// Round 11
// 244.238 us; speedup vs baseline: 1.6979x; 1.2027x over previous
//
#include <hip/hip_runtime.h>
#include <hip/hip_bf16.h>

#define CLS 225      // number of classes
#define OPC 224      // outputs per class
#define DIM 1024     // input dim
#define NTOK 1024    // tokens = 8*128
#define VOCAB 50257

#define BM 128       // rows per block (main kernel)
#define BK 32        // K-step
#define NT 14        // 224/16 N-tiles

typedef __attribute__((ext_vector_type(8))) short bf16x8;
typedef __attribute__((ext_vector_type(4))) float f32x4;

__device__ __forceinline__ unsigned short f2bf(float f) {
  unsigned u = __float_as_uint(f);
  u += 0x7FFFu + ((u >> 16) & 1u);
  return (unsigned short)(u >> 16);
}

// async global->LDS, 16B per lane. LDS dest = wave-uniform base + lane*16;
// global src is per-lane.
__device__ __forceinline__ void gll16(const void* gsrc, void* ldst) {
  __builtin_amdgcn_global_load_lds(
      (const __attribute__((address_space(1))) void*)gsrc,
      (__attribute__((address_space(3))) void*)ldst, 16, 0, 0);
}

// ---------------- merged prep: W2 convert (blocks 0..7199) + cls softmax
// + X->bf16 swizzled (blocks 7200..7455). One launch.
// W2 path v2: transpose-through-LDS. Read W2 rows coalesced (float4), stage in
// LDS (row stride 228 f32), then each thread INVERTS the swizzle index and
// stores its bf16x8 at contiguous byte q*16 -> fully coalesced 1KB/wave writes.
// Produces byte-identical W2ws to the previous store-side-swizzle version.
__global__ __launch_bounds__(256) void hs_prep(
    const float* __restrict__ X, const float* __restrict__ W1,
    const float* __restrict__ b1, float* __restrict__ cls,
    unsigned short* __restrict__ Xws,
    const float* __restrict__ W2, unsigned short* __restrict__ W2ws)
{
  const int bid = blockIdx.x;
  const int tid = threadIdx.x;

  // aliased LDS: W2 path uses ks[32*228] f32 (29184 B);
  // cls path uses xs[4][DIM] (16384 B) + lg[4][CLS] (3600 B).
  __shared__ __align__(16) char smem[29184];
  float* ks = (float*)smem;
  float (*xs)[DIM] = (float (*)[DIM])smem;
  float (*lg)[CLS] = (float (*)[CLS])(smem + 16384);

  if (bid < CLS * 32) {
    const int ct = bid;
    const int c = ct >> 5, t = ct & 31;
    const float* src = W2 + ((size_t)c * DIM + (size_t)t * 32) * OPC;
    char* dst = (char*)(W2ws + (size_t)ct * (OPC * 32));

    // stage 32 k-rows x 224 f32, coalesced float4 (1792 float4, 7/thread)
#pragma unroll
    for (int r = 0; r < 7; ++r) {
      const int i = tid + r * 256;
      const int k = i / 56, cc = (i % 56) * 4;
      *(float4*)&ks[k * 228 + cc] = *(const float4*)(src + (size_t)k * OPC + cc);
    }
    __syncthreads();

    // convert + contiguous store: 16B slot q -> (o, slot) via swizzle inverse
#pragma unroll
    for (int r = 0; r < 4; ++r) {
      const int q = tid + r * 256;
      if (q < 896) {
        const int rr = q >> 2, s = q & 3;
        const int o = rr ^ ((rr >> 2) & 1);
        const int slot = s ^ (o & 3);
        const float* f = &ks[slot * 8 * 228 + o];
        bf16x8 pk;
#pragma unroll
        for (int j = 0; j < 8; ++j) pk[j] = (short)f2bf(f[j * 228]);
        *(bf16x8*)(dst + q * 16) = pk;
      }
    }
    return;
  }

  // ---- class softmax (f32, exact) + Xws emit ----
  const int r0 = (bid - CLS * 32) * 4;

  {
    const float4* src = (const float4*)(X + (size_t)r0 * DIM);
    float4* dst = (float4*)xs;
    for (int i = tid; i < 4 * DIM / 4; i += 256) dst[i] = src[i];
  }
  __syncthreads();

  // Xws tile t (64KB): byte (n*64 + slot*16) ^ ((n&7)<<4) = X[n][t*32+slot*8+j]
  for (int i = tid; i < 512; i += 256) {
    const int r = i >> 7, grp = i & 127;
    const int t = grp >> 2, slot = grp & 3;
    const int n = r0 + r;
    const float* p = &xs[r][t * 32 + slot * 8];
    bf16x8 pk;
#pragma unroll
    for (int j = 0; j < 8; ++j) pk[j] = (short)f2bf(p[j]);
    const int wb = (n * 64 + slot * 16) ^ ((n & 7) << 4);
    *(bf16x8*)((char*)Xws + (size_t)t * 65536 + wb) = pk;
  }

  if (tid < CLS) {
    float acc0 = 0.f, acc1 = 0.f, acc2 = 0.f, acc3 = 0.f;
    const float* w1p = W1 + tid;
    for (int d = 0; d < DIM; d += 8) {
      float w[8];
#pragma unroll
      for (int u = 0; u < 8; ++u) w[u] = w1p[(size_t)(d + u) * CLS];
#pragma unroll
      for (int u = 0; u < 8; ++u) {
        acc0 += xs[0][d + u] * w[u];
        acc1 += xs[1][d + u] * w[u];
        acc2 += xs[2][d + u] * w[u];
        acc3 += xs[3][d + u] * w[u];
      }
    }
    const float bb = b1[tid];
    lg[0][tid] = acc0 + bb;
    lg[1][tid] = acc1 + bb;
    lg[2][tid] = acc2 + bb;
    lg[3][tid] = acc3 + bb;
  }
  __syncthreads();

  const int wave = tid >> 6, lane = tid & 63;
  {
    const int r = wave;
    float v[4];
    float m = -1e30f;
#pragma unroll
    for (int i = 0; i < 4; ++i) {
      const int c2 = lane + i * 64;
      v[i] = (c2 < CLS) ? lg[r][c2] : -1e30f;
      m = fmaxf(m, v[i]);
    }
#pragma unroll
    for (int mask = 32; mask >= 1; mask >>= 1) m = fmaxf(m, __shfl_xor(m, mask));
    float e[4];
    float s = 0.f;
#pragma unroll
    for (int i = 0; i < 4; ++i) {
      const int c2 = lane + i * 64;
      e[i] = (c2 < CLS) ? __expf(v[i] - m) : 0.f;
      s += e[i];
    }
#pragma unroll
    for (int mask = 32; mask >= 1; mask >>= 1) s += __shfl_xor(s, mask);
    const float inv = 1.f / s;
#pragma unroll
    for (int i = 0; i < 4; ++i) {
      const int c2 = lane + i * 64;
      if (c2 < CLS) cls[(size_t)(r0 + r) * CLS + c2] = e[i] * inv;
    }
  }
}

// standalone cls kernel (fallback path)
__global__ __launch_bounds__(256) void hs_cls_kernel(
    const float* __restrict__ X, const float* __restrict__ W1,
    const float* __restrict__ b1, float* __restrict__ cls)
{
  const int r0 = blockIdx.x * 4;
  const int tid = threadIdx.x;

  __shared__ float xs[4][DIM];
  __shared__ float lg[4][CLS];

  {
    const float4* src = (const float4*)(X + (size_t)r0 * DIM);
    float4* dst = (float4*)xs;
    for (int i = tid; i < 4 * DIM / 4; i += 256) dst[i] = src[i];
  }
  __syncthreads();

  if (tid < CLS) {
    float acc0 = 0.f, acc1 = 0.f, acc2 = 0.f, acc3 = 0.f;
    const float* w1p = W1 + tid;
    for (int d = 0; d < DIM; d += 8) {
      float w[8];
#pragma unroll
      for (int u = 0; u < 8; ++u) w[u] = w1p[(size_t)(d + u) * CLS];
#pragma unroll
      for (int u = 0; u < 8; ++u) {
        acc0 += xs[0][d + u] * w[u];
        acc1 += xs[1][d + u] * w[u];
        acc2 += xs[2][d + u] * w[u];
        acc3 += xs[3][d + u] * w[u];
      }
    }
    const float bb = b1[tid];
    lg[0][tid] = acc0 + bb;
    lg[1][tid] = acc1 + bb;
    lg[2][tid] = acc2 + bb;
    lg[3][tid] = acc3 + bb;
  }
  __syncthreads();

  const int wave = tid >> 6, lane = tid & 63;
  {
    const int r = wave;
    float v[4];
    float m = -1e30f;
#pragma unroll
    for (int i = 0; i < 4; ++i) {
      const int c2 = lane + i * 64;
      v[i] = (c2 < CLS) ? lg[r][c2] : -1e30f;
      m = fmaxf(m, v[i]);
    }
#pragma unroll
    for (int mask = 32; mask >= 1; mask >>= 1) m = fmaxf(m, __shfl_xor(m, mask));
    float e[4];
    float s = 0.f;
#pragma unroll
    for (int i = 0; i < 4; ++i) {
      const int c2 = lane + i * 64;
      e[i] = (c2 < CLS) ? __expf(v[i] - m) : 0.f;
      s += e[i];
    }
#pragma unroll
    for (int mask = 32; mask >= 1; mask >>= 1) s += __shfl_xor(s, mask);
    const float inv = 1.f / s;
#pragma unroll
    for (int i = 0; i < 4; ++i) {
      const int c2 = lane + i * 64;
      if (c2 < CLS) cls[(size_t)(r0 + r) * CLS + c2] = e[i] * inv;
    }
  }
}

// linear Xbf for the fallback path
__global__ __launch_bounds__(256) void x_convert_linear(
    const float* __restrict__ X, unsigned short* __restrict__ Xbf)
{
  const int r0 = blockIdx.x * 16;
  for (int i = threadIdx.x; i < 16 * 128; i += 256) {
    const int r = i >> 7, grp = i & 127;
    const int n = r0 + r;
    const float* p = X + (size_t)n * DIM + grp * 8;
    bf16x8 pk;
#pragma unroll
    for (int j = 0; j < 8; ++j) pk[j] = (short)f2bf(p[j]);
    *(bf16x8*)(Xbf + (size_t)n * DIM + grp * 8) = pk;
  }
}

// ---------------- main: counted-vmcnt double-buffered GEMM + fused softmax ----------------
// EXACT round-5 structure (measured 170 us, VGPR 128, occupancy 19.4%):
// row partition (wave wv owns rows [wv*32, wv*32+32)), 2 A-frags + 14 B-frags,
// T4 counted vmcnt(6), raw barriers, b2v epilogue with 16-lane shfl softmax.
__global__ __launch_bounds__(256, 1) void hs_main2(
    const unsigned short* __restrict__ W2ws, const float* __restrict__ b2,
    const unsigned short* __restrict__ Xws, const float* __restrict__ cls,
    float* __restrict__ out)
{
  const int bid = blockIdx.x;
  const int g = bid >> 6;
  const int xcd = bid & 7;
  const int rt = (bid >> 3) & 7;
  const int c = g * 8 + xcd;
  if (c >= CLS) return;
  const int n0 = rt * BM;

  // Bs padded to 16 segments (rows 224..255 garbage, never read); source
  // overrun (<=2KB) of the last tile lands in Xws (follows W2ws in ws).
  __shared__ __align__(16) char As[2][8192];
  __shared__ __align__(16) char Bs[2][16384];

  const int tid = threadIdx.x;
  const int wv = tid >> 6, lane = tid & 63;
  const int lo16 = lane & 15, hi4 = lane >> 4;
  const int loff = lane * 16;

  f32x4 acc[2][NT];
#pragma unroll
  for (int mt = 0; mt < 2; ++mt)
#pragma unroll
    for (int nt = 0; nt < NT; ++nt) acc[mt][nt] = (f32x4){0.f, 0.f, 0.f, 0.f};

  // per-wave staging segments: s = wv*6+i; s<8 -> A seg s, else B seg s-8.
  const char* xb  = (const char*)Xws + (size_t)n0 * 64 + loff;
  const char* wb2 = (const char*)W2ws + (size_t)c * 32 * 14336 + loff;
#define SEGDEF(i)                                                              \
  const int s_##i = wv * 6 + i;                                                \
  const bool isA_##i = (s_##i < 8);                                            \
  const char* g_##i = isA_##i ? (xb + s_##i * 1024) : (wb2 + (s_##i - 8) * 1024); \
  const size_t gstr_##i = isA_##i ? 65536u : 14336u;                           \
  const int ldo_##i = isA_##i ? s_##i * 1024 : (s_##i - 8) * 1024;
  SEGDEF(0) SEGDEF(1) SEGDEF(2) SEGDEF(3) SEGDEF(4) SEGDEF(5)

#define STG(i, buf, t)                                                         \
  gll16(g_##i + (size_t)(t) * gstr_##i, (isA_##i ? As[buf] : Bs[buf]) + ldo_##i)
#define STAGE(buf, t)                                                          \
  { STG(0, buf, t); STG(1, buf, t); STG(2, buf, t); STG(3, buf, t);            \
    STG(4, buf, t); STG(5, buf, t); }

#define COMPUTE(buf)                                                           \
  {                                                                            \
    const char* Ac = As[buf];                                                  \
    const char* Bc = Bs[buf];                                                  \
    const int ra = wv * 32 + lo16;                                             \
    const int axor = (lo16 & 7) << 4;                                          \
    const bf16x8 va0 = *(const bf16x8*)(Ac + ((ra * 64 + hi4 * 16) ^ axor));   \
    const bf16x8 va1 = *(const bf16x8*)(Ac + (((ra + 16) * 64 + hi4 * 16) ^ axor)); \
    _Pragma("unroll")                                                          \
    for (int nt = 0; nt < NT; ++nt) {                                          \
      const int o = nt * 16 + lo16;                                            \
      const bf16x8 vb = *(const bf16x8*)(Bc + ((o * 64 + hi4 * 16) ^ ((o & 7) << 4))); \
      acc[0][nt] = __builtin_amdgcn_mfma_f32_16x16x32_bf16(va0, vb, acc[0][nt], 0, 0, 0); \
      acc[1][nt] = __builtin_amdgcn_mfma_f32_16x16x32_bf16(va1, vb, acc[1][nt], 0, 0, 0); \
    }                                                                          \
  }

  STAGE(0, 0);                       // tile 0 -> buf0 (6 loads)
  STAGE(1, 1);                       // tile 1 -> buf1 (12 outstanding)

  for (int t = 0; t < 31; ++t) {
    // own tile-t loads done; tile-(t+1)'s 6 stay in flight (never drain to 0)
    asm volatile("s_waitcnt vmcnt(6)" ::: "memory");
    __builtin_amdgcn_s_barrier();
    __builtin_amdgcn_sched_barrier(0);   // pin ds_reads after the barrier

    COMPUTE(t & 1);

    __builtin_amdgcn_sched_barrier(0);   // pin compute before the barrier
    __builtin_amdgcn_s_barrier();        // all waves done reading buf[t&1]
    if (t < 30) STAGE(t & 1, t + 2);     // overwrite it with tile t+2
  }
  // tail: tile 31 (in buf1), 6 loads outstanding
  asm volatile("s_waitcnt vmcnt(0)" ::: "memory");
  __builtin_amdgcn_s_barrier();
  __builtin_amdgcn_sched_barrier(0);
  COMPUTE(1);

#undef STAGE
#undef STG
#undef SEGDEF
#undef COMPUTE

  // ---- epilogue: +b2, row softmax over 224, scale by class prob, store ----
  float b2v[NT];
#pragma unroll
  for (int nt = 0; nt < NT; ++nt) b2v[nt] = b2[c * OPC + nt * 16 + lo16];

#pragma unroll
  for (int mt = 0; mt < 2; ++mt) {
#pragma unroll
    for (int j = 0; j < 4; ++j) {
      const int n = n0 + wv * 32 + mt * 16 + hi4 * 4 + j;
      float vv[NT];
      float m = -1e30f;
#pragma unroll
      for (int nt = 0; nt < NT; ++nt) {
        vv[nt] = acc[mt][nt][j] + b2v[nt];
        m = fmaxf(m, vv[nt]);
      }
#pragma unroll
      for (int mask = 8; mask >= 1; mask >>= 1) m = fmaxf(m, __shfl_xor(m, mask));
      float s = 0.f;
#pragma unroll
      for (int nt = 0; nt < NT; ++nt) {
        vv[nt] = __expf(vv[nt] - m);
        s += vv[nt];
      }
#pragma unroll
      for (int mask = 8; mask >= 1; mask >>= 1) s += __shfl_xor(s, mask);
      const float scale = cls[(size_t)n * CLS + c] / s;
      const size_t rowbase = (size_t)n * VOCAB;
      const int colbase = c * OPC + lo16;
#pragma unroll
      for (int nt = 0; nt < NT; ++nt) {
        const int col = colbase + nt * 16;
        if (col < VOCAB)
          __builtin_nontemporal_store(vv[nt] * scale, out + rowbase + col);
      }
    }
  }
}

// ---------------- fallback main (round-1, known-passing): inline convert ----------------
__global__ __launch_bounds__(256, 1) void hs_main_fallback(
    const float* __restrict__ W2, const float* __restrict__ b2,
    const unsigned short* __restrict__ Xbf, const float* __restrict__ cls,
    float* __restrict__ out)
{
  const int bid = blockIdx.x;
  const int g = bid >> 6;
  const int xcd = bid & 7;
  const int rt = (bid >> 3) & 7;
  const int c = g * 8 + xcd;
  if (c >= CLS) return;
  const int n0 = rt * BM;
  const float* __restrict__ W2c = W2 + (size_t)c * DIM * OPC;

  __shared__ __align__(16) char As[BM * BK * 2];
  __shared__ __align__(16) char Bs[OPC * BK * 2];

  const int tid = threadIdx.x;
  const int wv = tid >> 6, lane = tid & 63;
  const int lo16 = lane & 15, hi4 = lane >> 4;

  f32x4 acc[2][NT];
#pragma unroll
  for (int mt = 0; mt < 2; ++mt)
#pragma unroll
    for (int nt = 0; nt < NT; ++nt) acc[mt][nt] = (f32x4){0.f, 0.f, 0.f, 0.f};

  const int an0 = tid >> 2;
  const int akp = tid & 3;

  for (int k0 = 0; k0 < DIM; k0 += BK) {
    __syncthreads();
#pragma unroll
    for (int r = 0; r < 2; ++r) {
      const int n = an0 + r * 64;
      const uint4 raw = *(const uint4*)(Xbf + (size_t)(n0 + n) * DIM + k0 + akp * 8);
      const int wb = (n * 64 + akp * 16) ^ ((n & 7) << 4);
      *(uint4*)(As + wb) = raw;
    }
#pragma unroll
    for (int r = 0; r < 4; ++r) {
      const int t = tid + r * 256;
      if (t < 896) {
        const int o = t % OPC;
        const int kg = t / OPC;
        const float* p = W2c + (size_t)(k0 + kg * 8) * OPC + o;
        bf16x8 pk;
#pragma unroll
        for (int j = 0; j < 8; ++j) pk[j] = (short)f2bf(p[(size_t)j * OPC]);
        const int wb = (o * 64 + kg * 16) ^ ((o & 7) << 4);
        *(bf16x8*)(Bs + wb) = pk;
      }
    }
    __syncthreads();

    const int ra = wv * 32 + lo16;
    const int axor = (lo16 & 7) << 4;
    const bf16x8 a0 = *(const bf16x8*)(As + ((ra * 64 + hi4 * 16) ^ axor));
    const bf16x8 a1 = *(const bf16x8*)(As + (((ra + 16) * 64 + hi4 * 16) ^ axor));
#pragma unroll
    for (int nt = 0; nt < NT; ++nt) {
      const int o = nt * 16 + lo16;
      const bf16x8 b = *(const bf16x8*)(Bs + ((o * 64 + hi4 * 16) ^ ((o & 7) << 4)));
      acc[0][nt] = __builtin_amdgcn_mfma_f32_16x16x32_bf16(a0, b, acc[0][nt], 0, 0, 0);
      acc[1][nt] = __builtin_amdgcn_mfma_f32_16x16x32_bf16(a1, b, acc[1][nt], 0, 0, 0);
    }
  }

  float b2v[NT];
#pragma unroll
  for (int nt = 0; nt < NT; ++nt) b2v[nt] = b2[c * OPC + nt * 16 + lo16];

#pragma unroll
  for (int mt = 0; mt < 2; ++mt) {
#pragma unroll
    for (int j = 0; j < 4; ++j) {
      const int n = n0 + wv * 32 + mt * 16 + hi4 * 4 + j;
      float vv[NT];
      float m = -1e30f;
#pragma unroll
      for (int nt = 0; nt < NT; ++nt) {
        vv[nt] = acc[mt][nt][j] + b2v[nt];
        m = fmaxf(m, vv[nt]);
      }
#pragma unroll
      for (int mask = 8; mask >= 1; mask >>= 1) m = fmaxf(m, __shfl_xor(m, mask));
      float s = 0.f;
#pragma unroll
      for (int nt = 0; nt < NT; ++nt) {
        vv[nt] = __expf(vv[nt] - m);
        s += vv[nt];
      }
#pragma unroll
      for (int mask = 8; mask >= 1; mask >>= 1) s += __shfl_xor(s, mask);
      const float scale = cls[(size_t)n * CLS + c] / s;
      const size_t rowbase = (size_t)n * VOCAB;
      const int colbase = c * OPC + lo16;
#pragma unroll
      for (int nt = 0; nt < NT; ++nt) {
        const int col = colbase + nt * 16;
        if (col < VOCAB)
          __builtin_nontemporal_store(vv[nt] * scale, out + rowbase + col);
      }
    }
  }
}

extern "C" void kernel_launch(void* const* d_in, const int* in_sizes, int n_in,
                              void* d_out, int out_size, void* d_ws, size_t ws_size,
                              hipStream_t stream) {
  const float* X  = (const float*)d_in[0];
  const float* W1 = (const float*)d_in[1];
  const float* b1 = (const float*)d_in[2];
  const float* W2 = (const float*)d_in[3];
  const float* b2 = (const float*)d_in[4];
  float* out = (float*)d_out;

  const size_t W2WS = (size_t)CLS * DIM * OPC * 2;   // 103,219,200 B
  const size_t XWS  = (size_t)NTOK * DIM * 2;        //   2,097,152 B (also absorbs B-stage overrun)
  const size_t CLSZ = (size_t)NTOK * CLS * 4;        //     921,600 B

  if (ws_size >= W2WS + XWS + CLSZ) {
    unsigned short* W2ws = (unsigned short*)d_ws;
    unsigned short* Xws  = (unsigned short*)((char*)d_ws + W2WS);
    float* cls = (float*)((char*)d_ws + W2WS + XWS);

    hs_prep<<<CLS * 32 + NTOK / 4, 256, 0, stream>>>(X, W1, b1, cls, Xws, W2, W2ws);
    hs_main2<<<29 * 64, 256, 0, stream>>>(W2ws, b2, Xws, cls, out);
  } else {
    unsigned short* Xbf = (unsigned short*)d_ws;
    float* cls = (float*)((char*)d_ws + (size_t)NTOK * DIM * 2);

    x_convert_linear<<<NTOK / 16, 256, 0, stream>>>(X, Xbf);
    hs_cls_kernel<<<NTOK / 4, 256, 0, stream>>>(X, W1, b1, cls);
    hs_main_fallback<<<29 * 64, 256, 0, stream>>>(W2, b2, Xbf, cls, out);
  }
}